// Round 1
// baseline (2417.783 us; speedup 1.0000x reference)
//
#include <hip/hip_runtime.h>
#include <stdint.h>

typedef _Float16 f16;
typedef _Float16 h2 __attribute__((ext_vector_type(2)));
typedef float f4 __attribute__((ext_vector_type(4)));

union F4H { f4 v; h2 h[4]; f16 s[8]; };

__device__ __forceinline__ float fdot2(h2 a, h2 b, float c) {
    return __builtin_amdgcn_fdot2(a, b, c, false);
}

#define NB 64
#define NT 512
#define NH 256
#define NG 1024

// ---------------- workspace layout ----------------
static const size_t OFF_H0   = 0;           // h0 f16  [64][512][256]   16,777,216 B
static const size_t OFF_X1   = 16777216;    // x1 f16  [64*512][1024]   67,108,864 B
static const size_t OFF_H1   = 83886080;    // h1 f16  [64][512][256]   16,777,216 B
static const size_t OFF_PL0  = 100663296;   // packed Whh0 [32][1024] f4  524,288 B
static const size_t OFF_PL1  = 101187584;   // packed Whh1                524,288 B
static const size_t OFF_WIH1 = 101711872;   // packed Wih1 [32][1024] f4  524,288 B
static const size_t OFF_WX0  = 102236160;   // wx0 h2 [4][1024]            16,384 B
static const size_t OFF_B0C  = 102252544;   // bias0c f32 [1024]            4,096 B
static const size_t OFF_B1C  = 102256640;   // bias1c f32 [1024]            4,096 B
static const size_t OFF_WR1  = 102260736;   // wr1p f4 [32][128]           65,536 B
static const size_t OFF_MM   = 102326272;   // mmean f32 [64][256]         65,536 B
static const size_t OFF_M1S  = 102391808;   // m1sum f32 [64][128]         32,768 B
static const size_t OFF_HL   = 102424576;   // hh1last f32 [64][128]       32,768 B

// ---------------- packing kernels ----------------
// [1024][256] f32 row-major -> [32 k-groups][1024 cols] f4 (8 f16 each)
__global__ void pack_w256(const float* __restrict__ src, f4* __restrict__ dst)
{
    const int id = blockIdx.x * 256 + threadIdx.x;   // 32768 tasks
    const int j = id >> 5;
    const int g = id & 31;
    const float* s = src + j * 256 + g * 8;
    F4H u;
    #pragma unroll
    for (int i = 0; i < 8; ++i) u.s[i] = (f16)s[i];
    dst[g * 1024 + j] = u.v;
}

__global__ void pack_misc(const float* __restrict__ bih0, const float* __restrict__ bhh0,
                          const float* __restrict__ bih1, const float* __restrict__ bhh1,
                          const float* __restrict__ wih0, const float* __restrict__ wr1,
                          float* __restrict__ bias0c, float* __restrict__ bias1c,
                          h2* __restrict__ wx0p, f4* __restrict__ wr1p)
{
    const int id = blockIdx.x * 256 + threadIdx.x;   // 10240 tasks
    if (id < 1024) {
        bias0c[id] = bih0[id] + bhh0[id];
    } else if (id < 2048) {
        const int j = id - 1024;
        bias1c[j] = bih1[j] + bhh1[j];
    } else if (id < 6144) {
        const int q = id - 2048;
        const int p = q >> 10, j = q & 1023;
        h2 v; v[0] = (f16)wih0[j * 8 + 2 * p]; v[1] = (f16)wih0[j * 8 + 2 * p + 1];
        wx0p[p * 1024 + j] = v;
    } else {
        const int q = id - 6144;
        const int g = q >> 7, o = q & 127;
        F4H u;
        #pragma unroll
        for (int i = 0; i < 8; ++i)
            u.s[i] = (o < 100) ? (f16)wr1[o * 256 + g * 8 + i] : (f16)0.f;
        wr1p[g * 128 + o] = u.v;
    }
}

// ---------------- LSTM chain kernel ----------------
// one workgroup (512 threads) per batch element; thread t owns gate cols t and t+512.
// k-split (32 groups of 8): [0,3) LDS, [3,25) registers, [25,28)+[28,32) streamed.
template<int LAYER>
__global__ __launch_bounds__(512, 2)
void lstm_chain(const float* __restrict__ x,
                const f16* __restrict__ x1,
                const f4* __restrict__ pack,
                const float* __restrict__ biasc,
                const h2* __restrict__ wx0p,
                f16* __restrict__ hout,
                float* __restrict__ mmean)
{
    __shared__ f4 wlds[3 * 1024];                 // 48 KB
    __shared__ float gates[1024];                 // 4 KB
    __shared__ __align__(16) f16 hsh[256];        // 512 B
    __shared__ h2 xsh[512 * 4];                   // 8 KB (layer 0 only)

    const int t = threadIdx.x;
    const int b = blockIdx.x;
    const int j0 = t, j1 = t + 512;

    #pragma unroll
    for (int i = 0; i < 6; ++i) wlds[t + 512 * i] = pack[t + 512 * i];

    f4 wrA[22], wrB[22];
    #pragma unroll
    for (int g = 0; g < 22; ++g) {
        wrA[g] = pack[(3 + g) * 1024 + j0];
        wrB[g] = pack[(3 + g) * 1024 + j1];
    }

    float bc0 = 0.f, bc1 = 0.f;
    h2 wxA[4], wxB[4];
    if (LAYER == 0) {
        bc0 = biasc[j0]; bc1 = biasc[j1];
        #pragma unroll
        for (int p = 0; p < 4; ++p) { wxA[p] = wx0p[p * 1024 + j0]; wxB[p] = wx0p[p * 1024 + j1]; }
        const float* xb = x + ((size_t)b * NT + t) * 8;
        #pragma unroll
        for (int p = 0; p < 4; ++p) {
            h2 v; v[0] = (f16)xb[2 * p]; v[1] = (f16)xb[2 * p + 1];
            xsh[t * 4 + p] = v;
        }
    }
    if (t < 32) { f4 zz = {0.f, 0.f, 0.f, 0.f}; ((f4*)hsh)[t] = zz; }

    float cst = 0.f, hsum = 0.f;
    __syncthreads();

    const f4* strA = pack + 25 * 1024;
    const f4* strBp = pack + 28 * 1024;
    f16* houtb = hout + (size_t)b * NT * NH;
    const f16* x1b = (LAYER == 1) ? (x1 + (size_t)b * NT * NG) : (const f16*)nullptr;

    #pragma unroll 1
    for (int tt = 0; tt < NT; ++tt) {
        // stream batch A issue (groups 25..27)
        f4 sA0[3], sA1[3];
        #pragma unroll
        for (int g = 0; g < 3; ++g) { sA0[g] = strA[g * 1024 + j0]; sA1[g] = strA[g * 1024 + j1]; }

        float a0, a1, a0b = 0.f, a1b = 0.f;
        if (LAYER == 0) {
            a0 = bc0; a1 = bc1;
            #pragma unroll
            for (int p = 0; p < 4; ++p) {
                h2 xv = xsh[tt * 4 + p];
                a0 = fdot2(wxA[p], xv, a0);
                a1 = fdot2(wxB[p], xv, a1);
            }
        } else {
            const f16* xr = x1b + (size_t)tt * NG;
            a0 = (float)xr[j0];
            a1 = (float)xr[j1];
        }

        const f4* hv4 = (const f4*)hsh;

        // LDS region: groups 0..2
        #pragma unroll
        for (int i = 0; i < 3; ++i) {
            F4H hh; hh.v = hv4[i];
            F4H wa; wa.v = wlds[i * 1024 + j0];
            F4H wb; wb.v = wlds[i * 1024 + j1];
            #pragma unroll
            for (int q = 0; q < 4; ++q) {
                if (q & 1) { a0b = fdot2(wa.h[q], hh.h[q], a0b); a1b = fdot2(wb.h[q], hh.h[q], a1b); }
                else       { a0  = fdot2(wa.h[q], hh.h[q], a0 ); a1  = fdot2(wb.h[q], hh.h[q], a1 ); }
            }
        }
        // register region part 1: groups 3..13
        #pragma unroll
        for (int g = 0; g < 11; ++g) {
            F4H hh; hh.v = hv4[3 + g];
            F4H wa; wa.v = wrA[g];
            F4H wb; wb.v = wrB[g];
            #pragma unroll
            for (int q = 0; q < 4; ++q) {
                if (q & 1) { a0b = fdot2(wa.h[q], hh.h[q], a0b); a1b = fdot2(wb.h[q], hh.h[q], a1b); }
                else       { a0  = fdot2(wa.h[q], hh.h[q], a0 ); a1  = fdot2(wb.h[q], hh.h[q], a1 ); }
            }
        }
        // consume stream batch A (groups 25..27)
        #pragma unroll
        for (int g = 0; g < 3; ++g) {
            F4H hh; hh.v = hv4[25 + g];
            F4H wa; wa.v = sA0[g];
            F4H wb; wb.v = sA1[g];
            #pragma unroll
            for (int q = 0; q < 4; ++q) {
                if (q & 1) { a0b = fdot2(wa.h[q], hh.h[q], a0b); a1b = fdot2(wb.h[q], hh.h[q], a1b); }
                else       { a0  = fdot2(wa.h[q], hh.h[q], a0 ); a1  = fdot2(wb.h[q], hh.h[q], a1 ); }
            }
        }
        // stream batch B issue (groups 28..31)
        f4 sB0[4], sB1[4];
        #pragma unroll
        for (int g = 0; g < 4; ++g) { sB0[g] = strBp[g * 1024 + j0]; sB1[g] = strBp[g * 1024 + j1]; }
        // register region part 2: groups 14..24
        #pragma unroll
        for (int g = 11; g < 22; ++g) {
            F4H hh; hh.v = hv4[3 + g];
            F4H wa; wa.v = wrA[g];
            F4H wb; wb.v = wrB[g];
            #pragma unroll
            for (int q = 0; q < 4; ++q) {
                if (q & 1) { a0b = fdot2(wa.h[q], hh.h[q], a0b); a1b = fdot2(wb.h[q], hh.h[q], a1b); }
                else       { a0  = fdot2(wa.h[q], hh.h[q], a0 ); a1  = fdot2(wb.h[q], hh.h[q], a1 ); }
            }
        }
        // consume stream batch B (groups 28..31)
        #pragma unroll
        for (int g = 0; g < 4; ++g) {
            F4H hh; hh.v = hv4[28 + g];
            F4H wa; wa.v = sB0[g];
            F4H wb; wb.v = sB1[g];
            #pragma unroll
            for (int q = 0; q < 4; ++q) {
                if (q & 1) { a0b = fdot2(wa.h[q], hh.h[q], a0b); a1b = fdot2(wb.h[q], hh.h[q], a1b); }
                else       { a0  = fdot2(wa.h[q], hh.h[q], a0 ); a1  = fdot2(wb.h[q], hh.h[q], a1 ); }
            }
        }

        gates[j0] = a0 + a0b;
        gates[j1] = a1 + a1b;
        __syncthreads();

        if (t < 256) {
            float gi = gates[t];
            float gf = gates[t + 256];
            float gg = gates[t + 512];
            float go = gates[t + 768];
            float si = 1.f / (1.f + __expf(-gi));
            float sf = 1.f / (1.f + __expf(-gf));
            float so = 1.f / (1.f + __expf(-go));
            float tg = 1.f - 2.f / (__expf(2.f * gg) + 1.f);   // tanh, NaN-safe
            cst = sf * cst + si * tg;
            float th = 1.f - 2.f / (__expf(2.f * cst) + 1.f);
            float hvl = so * th;
            hsh[t] = (f16)hvl;
            if (LAYER == 1) hsum += hvl;
        }
        __syncthreads();

        if (t < 32) ((f4*)(houtb + (size_t)tt * NH))[t] = ((const f4*)hsh)[t];
    }
    if (LAYER == 1 && t < 256) mmean[b * NH + t] = hsum * (1.f / 512.f);
}

// ---------------- K2: x1 = h0 @ Wih1^T + bias1 ----------------
__global__ __launch_bounds__(256)
void k2_gemm(const f16* __restrict__ h0, const f4* __restrict__ wih1p,
             const float* __restrict__ b1c, f16* __restrict__ x1)
{
    __shared__ __align__(16) f16 ash[64 * 256];   // 32 KB A-tile (64 rows x 256 k)
    const int l = threadIdx.x;
    const size_t m0 = (size_t)blockIdx.x * 64;
    const f4* src = (const f4*)(h0 + m0 * 256);
    f4* dst = (f4*)ash;
    #pragma unroll
    for (int i = 0; i < 8; ++i) dst[l + 256 * i] = src[l + 256 * i];
    __syncthreads();

    const int lane = l & 63;
    const int rg4 = l >> 6;
    #pragma unroll 1
    for (int pass = 0; pass < 16; ++pass) {
        const int rgrp = pass >> 2;
        const int nc = pass & 3;
        const int row0 = rgrp * 16 + rg4 * 4;
        const int col0 = nc * 256 + lane;
        float acc[4][4];
        float bq[4];
        #pragma unroll
        for (int q = 0; q < 4; ++q) bq[q] = b1c[col0 + 64 * q];
        #pragma unroll
        for (int r = 0; r < 4; ++r)
            #pragma unroll
            for (int q = 0; q < 4; ++q) acc[r][q] = bq[q];

        for (int u = 0; u < 32; ++u) {
            f4 wv[4];
            #pragma unroll
            for (int q = 0; q < 4; ++q) wv[q] = wih1p[u * 1024 + col0 + 64 * q];
            #pragma unroll
            for (int r = 0; r < 4; ++r) {
                F4H av; av.v = ((const f4*)ash)[(row0 + r) * 32 + u];
                #pragma unroll
                for (int q = 0; q < 4; ++q) {
                    F4H wq; wq.v = wv[q];
                    #pragma unroll
                    for (int p = 0; p < 4; ++p) acc[r][q] = fdot2(av.h[p], wq.h[p], acc[r][q]);
                }
            }
        }
        #pragma unroll
        for (int r = 0; r < 4; ++r)
            #pragma unroll
            for (int q = 0; q < 4; ++q)
                x1[(m0 + row0 + r) * 1024 + col0 + 64 * q] = (f16)acc[r][q];
    }
}

// ---------------- K4a: hh1 = elu(m@Wl1^T + b1 + h1@Wr1^T); partial sums for m1 ----------------
__global__ __launch_bounds__(256)
void k4a(const f16* __restrict__ h1, const float* __restrict__ mmean,
         const float* __restrict__ Wl1, const float* __restrict__ b1,
         const f4* __restrict__ wr1p, float* __restrict__ m1sum,
         float* __restrict__ hh1last)
{
    __shared__ __align__(16) f16 ash[64 * 256];   // 32 KB h1 chunk
    __shared__ float msh[256];
    __shared__ float mbase[128];
    __shared__ float red[256];
    const int l = threadIdx.x;
    const int b = blockIdx.x >> 3;
    const int ch = blockIdx.x & 7;

    const f4* src = (const f4*)(h1 + ((size_t)b * 512 + ch * 64) * 256);
    f4* dst = (f4*)ash;
    #pragma unroll
    for (int i = 0; i < 8; ++i) dst[l + 256 * i] = src[l + 256 * i];
    msh[l] = mmean[b * 256 + l];
    __syncthreads();

    if (l < 128) {
        float acc = 0.f;
        if (l < 100) {
            acc = b1[l];
            const float* wrow = Wl1 + l * 256;
            for (int j = 0; j < 256; ++j) acc += msh[j] * wrow[j];
        }
        mbase[l] = acc;
    }
    __syncthreads();

    const int o = l & 127;
    const int th = l >> 7;
    float sumloc = 0.f;
    float last = 0.f;
    #pragma unroll 1
    for (int it = 0; it < 32; ++it) {
        const int tloc = it * 2 + th;
        float acc = mbase[o];
        const f4* arow = (const f4*)(ash + tloc * 256);
        #pragma unroll
        for (int u = 0; u < 32; ++u) {
            F4H av; av.v = arow[u];
            F4H wv; wv.v = wr1p[u * 128 + o];
            #pragma unroll
            for (int p = 0; p < 4; ++p) acc = fdot2(av.h[p], wv.h[p], acc);
        }
        float e = acc > 0.f ? acc : (__expf(acc) - 1.f);
        sumloc += e;
        if (tloc == 63) last = e;
    }
    red[l] = sumloc;
    __syncthreads();
    if (l < 128) {
        float s = red[l] + red[l + 128];
        if (l < 100) atomicAdd(m1sum + b * 128 + l, s);
    }
    if (ch == 7 && th == 1) hh1last[b * 128 + o] = last;
}

// ---------------- K4b: final head (all fp32) ----------------
__global__ __launch_bounds__(128)
void k4b(const float* __restrict__ m1sum, const float* __restrict__ hh1last,
         const float* __restrict__ Wl2, const float* __restrict__ Wr2,
         const float* __restrict__ b2,
         const float* __restrict__ Wfc1, const float* __restrict__ bfc1,
         const float* __restrict__ Wfc2, const float* __restrict__ bfc2,
         float* __restrict__ out)
{
    __shared__ float m1s[128];
    __shared__ float hl[128];
    __shared__ float s[128];
    __shared__ float zsh[512];
    const int b = blockIdx.x;
    const int l = threadIdx.x;

    m1s[l] = m1sum[b * 128 + l] * (1.f / 512.f);
    hl[l] = hh1last[b * 128 + l];
    __syncthreads();

    {
        float acc = b2[l];
        const float* wl2r = Wl2 + l * 100;
        const float* wr2r = Wr2 + l * 100;
        for (int j = 0; j < 100; ++j) acc += m1s[j] * wl2r[j] + hl[j] * wr2r[j];
        s[l] = acc;
    }
    __syncthreads();

    #pragma unroll 1
    for (int i = 0; i < 4; ++i) {
        const int idx = l + 128 * i;
        const int k = idx >> 6, o = idx & 63;
        const float* w = Wfc1 + (size_t)(k * 64 + o) * 128;
        float a = bfc1[k * 64 + o];
        for (int d = 0; d < 128; ++d) a += s[d] * w[d];
        zsh[idx] = a > 0.f ? a : 0.f;
    }
    __syncthreads();

    #pragma unroll 1
    for (int i = 0; i < 2; ++i) {
        const int idx = l + 128 * i;
        if (idx < 192) {
            const int k = idx / 24, p = idx % 24;
            const float* w = Wfc2 + (size_t)(k * 24 + p) * 64;
            float a = bfc2[k * 24 + p];
            const float* z = zsh + k * 64;
            for (int d = 0; d < 64; ++d) a += z[d] * w[d];
            out[(size_t)(k * 64 + b) * 24 + p] = a;
        }
    }
}

// ---------------- launch ----------------
extern "C" void kernel_launch(void* const* d_in, const int* in_sizes, int n_in,
                              void* d_out, int out_size, void* d_ws, size_t ws_size,
                              hipStream_t stream)
{
    const float* x    = (const float*)d_in[0];
    const float* Wih0 = (const float*)d_in[1];
    const float* Whh0 = (const float*)d_in[2];
    const float* bih0 = (const float*)d_in[3];
    const float* bhh0 = (const float*)d_in[4];
    const float* Wih1 = (const float*)d_in[5];
    const float* Whh1 = (const float*)d_in[6];
    const float* bih1 = (const float*)d_in[7];
    const float* bhh1 = (const float*)d_in[8];
    const float* Wl1  = (const float*)d_in[9];
    const float* Wr1  = (const float*)d_in[10];
    const float* b1   = (const float*)d_in[11];
    const float* Wl2  = (const float*)d_in[12];
    const float* Wr2  = (const float*)d_in[13];
    const float* b2   = (const float*)d_in[14];
    const float* Wfc1 = (const float*)d_in[15];
    const float* bfc1 = (const float*)d_in[16];
    const float* Wfc2 = (const float*)d_in[17];
    const float* bfc2 = (const float*)d_in[18];

    char* ws = (char*)d_ws;
    f16*   h0f   = (f16*)(ws + OFF_H0);
    f16*   x1f   = (f16*)(ws + OFF_X1);
    f16*   h1f   = (f16*)(ws + OFF_H1);
    f4*    pl0   = (f4*)(ws + OFF_PL0);
    f4*    pl1   = (f4*)(ws + OFF_PL1);
    f4*    wih1p = (f4*)(ws + OFF_WIH1);
    h2*    wx0p  = (h2*)(ws + OFF_WX0);
    float* b0c   = (float*)(ws + OFF_B0C);
    float* b1c   = (float*)(ws + OFF_B1C);
    f4*    wr1p  = (f4*)(ws + OFF_WR1);
    float* mm    = (float*)(ws + OFF_MM);
    float* m1s   = (float*)(ws + OFF_M1S);
    float* hhl   = (float*)(ws + OFF_HL);

    // pack weights to fp16 layouts
    pack_w256<<<128, 256, 0, stream>>>(Whh0, pl0);
    pack_w256<<<128, 256, 0, stream>>>(Whh1, pl1);
    pack_w256<<<128, 256, 0, stream>>>(Wih1, wih1p);
    pack_misc<<<40, 256, 0, stream>>>(bih0, bhh0, bih1, bhh1, Wih0, Wr1,
                                      b0c, b1c, wx0p, wr1p);
    hipMemsetAsync(m1s, 0, 64 * 128 * sizeof(float), stream);

    // layer 0 chains
    lstm_chain<0><<<64, 512, 0, stream>>>(x, (const f16*)nullptr, pl0, b0c, wx0p, h0f, (float*)nullptr);
    // x1 = h0 @ Wih1^T + bias1
    k2_gemm<<<512, 256, 0, stream>>>(h0f, wih1p, b1c, x1f);
    // layer 1 chains (+ mean over t)
    lstm_chain<1><<<64, 512, 0, stream>>>((const float*)nullptr, x1f, pl1, (const float*)nullptr,
                                          (const h2*)nullptr, h1f, mm);
    // head
    k4a<<<512, 256, 0, stream>>>(h1f, mm, Wl1, b1, wr1p, m1s, hhl);
    k4b<<<64, 128, 0, stream>>>(m1s, hhl, Wl2, Wr2, b2, Wfc1, bfc1, Wfc2, bfc2, (float*)d_out);
}

// Round 3
// 2416.757 us; speedup vs baseline: 1.0004x; 1.0004x over previous
//
#include <hip/hip_runtime.h>
#include <stdint.h>

typedef _Float16 f16;
typedef _Float16 h2 __attribute__((ext_vector_type(2)));
typedef float f4 __attribute__((ext_vector_type(4)));

union F4H { f4 v; h2 h[4]; f16 s[8]; };

__device__ __forceinline__ float fdot2(h2 a, h2 b, float c) {
    return __builtin_amdgcn_fdot2(a, b, c, false);
}

#define NB 64
#define NT 512
#define NH 256
#define NG 1024

// ---------------- workspace layout ----------------
static const size_t OFF_H0   = 0;           // h0 f16  [64][512][256]   16,777,216 B
static const size_t OFF_X1   = 16777216;    // x1 f16  [64*512][1024]   67,108,864 B
static const size_t OFF_H1   = 83886080;    // h1 f16  [64][512][256]   16,777,216 B
static const size_t OFF_PL0  = 100663296;   // packed Whh0 [32][1024] f4  524,288 B
static const size_t OFF_PL1  = 101187584;   // packed Whh1                524,288 B
static const size_t OFF_WIH1 = 101711872;   // packed Wih1 [32][1024] f4  524,288 B
static const size_t OFF_WX0  = 102236160;   // wx0 h2 [4][1024]            16,384 B
static const size_t OFF_B0C  = 102252544;   // bias0c f32 [1024]            4,096 B
static const size_t OFF_B1C  = 102256640;   // bias1c f32 [1024]            4,096 B
static const size_t OFF_WR1  = 102260736;   // wr1p f4 [32][128]           65,536 B
static const size_t OFF_MM   = 102326272;   // mmean f32 [64][256]         65,536 B
static const size_t OFF_M1S  = 102391808;   // m1sum f32 [64][128]         32,768 B
static const size_t OFF_HL   = 102424576;   // hh1last f32 [64][128]       32,768 B

// ---------------- packing kernels (round-1 verbatim) ----------------
// [1024][256] f32 row-major -> [32 k-groups][1024 cols] f4 (8 f16 each)
__global__ void pack_w256(const float* __restrict__ src, f4* __restrict__ dst)
{
    const int id = blockIdx.x * 256 + threadIdx.x;   // 32768 tasks
    const int j = id >> 5;
    const int g = id & 31;
    const float* s = src + j * 256 + g * 8;
    F4H u;
    #pragma unroll
    for (int i = 0; i < 8; ++i) u.s[i] = (f16)s[i];
    dst[g * 1024 + j] = u.v;
}

__global__ void pack_misc(const float* __restrict__ bih0, const float* __restrict__ bhh0,
                          const float* __restrict__ bih1, const float* __restrict__ bhh1,
                          const float* __restrict__ wih0, const float* __restrict__ wr1,
                          float* __restrict__ bias0c, float* __restrict__ bias1c,
                          h2* __restrict__ wx0p, f4* __restrict__ wr1p)
{
    const int id = blockIdx.x * 256 + threadIdx.x;   // 10240 tasks
    if (id < 1024) {
        bias0c[id] = bih0[id] + bhh0[id];
    } else if (id < 2048) {
        const int j = id - 1024;
        bias1c[j] = bih1[j] + bhh1[j];
    } else if (id < 6144) {
        const int q = id - 2048;
        const int p = q >> 10, j = q & 1023;
        h2 v; v[0] = (f16)wih0[j * 8 + 2 * p]; v[1] = (f16)wih0[j * 8 + 2 * p + 1];
        wx0p[p * 1024 + j] = v;
    } else {
        const int q = id - 6144;
        const int g = q >> 7, o = q & 127;
        F4H u;
        #pragma unroll
        for (int i = 0; i < 8; ++i)
            u.s[i] = (o < 100) ? (f16)wr1[o * 256 + g * 8 + i] : (f16)0.f;
        wr1p[g * 128 + o] = u.v;
    }
}

// ---------------- LSTM chain kernel (round-1 structure) ----------------
// one workgroup (512 threads) per batch element; thread t owns gate cols t and t+512.
// k-split (32 groups of 8): [0,3) LDS, [3,21) registers, [21,26)+[26,32) streamed.
// amdgpu_waves_per_eu(2,2): pin to 2 waves/EU so the allocator uses the full
// 256-VGPR budget instead of round-1's 128-VGPR + ~100-reg spill.
template<int LAYER>
__global__
__attribute__((amdgpu_flat_work_group_size(512, 512)))
__attribute__((amdgpu_waves_per_eu(2, 2)))
void lstm_chain(const float* __restrict__ x,
                const f16* __restrict__ x1,
                const f4* __restrict__ pack,
                const float* __restrict__ biasc,
                const h2* __restrict__ wx0p,
                f16* __restrict__ hout,
                float* __restrict__ mmean)
{
    __shared__ f4 wlds[3 * 1024];                 // 48 KB
    __shared__ float gates[1024];                 // 4 KB
    __shared__ __align__(16) f16 hsh[256];        // 512 B
    __shared__ h2 xsh[512 * 4];                   // 8 KB (layer 0 only)

    const int t = threadIdx.x;
    const int b = blockIdx.x;
    const int j0 = t, j1 = t + 512;

    #pragma unroll
    for (int i = 0; i < 6; ++i) wlds[t + 512 * i] = pack[t + 512 * i];

    f4 wrA[18], wrB[18];
    #pragma unroll
    for (int g = 0; g < 18; ++g) {
        wrA[g] = pack[(3 + g) * 1024 + j0];
        wrB[g] = pack[(3 + g) * 1024 + j1];
    }

    float bc0 = 0.f, bc1 = 0.f;
    h2 wxA[4], wxB[4];
    if (LAYER == 0) {
        bc0 = biasc[j0]; bc1 = biasc[j1];
        #pragma unroll
        for (int p = 0; p < 4; ++p) { wxA[p] = wx0p[p * 1024 + j0]; wxB[p] = wx0p[p * 1024 + j1]; }
        const float* xb = x + ((size_t)b * NT + t) * 8;
        #pragma unroll
        for (int p = 0; p < 4; ++p) {
            h2 v; v[0] = (f16)xb[2 * p]; v[1] = (f16)xb[2 * p + 1];
            xsh[t * 4 + p] = v;
        }
    }
    if (t < 32) { f4 zz = {0.f, 0.f, 0.f, 0.f}; ((f4*)hsh)[t] = zz; }

    float cst = 0.f, hsum = 0.f;
    __syncthreads();

    const f4* strA = pack + 21 * 1024;
    const f4* strBp = pack + 26 * 1024;
    f16* houtb = hout + (size_t)b * NT * NH;
    const f16* x1b = (LAYER == 1) ? (x1 + (size_t)b * NT * NG) : (const f16*)nullptr;

    #pragma unroll 1
    for (int tt = 0; tt < NT; ++tt) {
        // stream batch A issue (groups 21..25)
        f4 sA0[5], sA1[5];
        #pragma unroll
        for (int g = 0; g < 5; ++g) { sA0[g] = strA[g * 1024 + j0]; sA1[g] = strA[g * 1024 + j1]; }

        float a0, a1, a0b = 0.f, a1b = 0.f;
        if (LAYER == 0) {
            a0 = bc0; a1 = bc1;
            #pragma unroll
            for (int p = 0; p < 4; ++p) {
                h2 xv = xsh[tt * 4 + p];
                a0 = fdot2(wxA[p], xv, a0);
                a1 = fdot2(wxB[p], xv, a1);
            }
        } else {
            const f16* xr = x1b + (size_t)tt * NG;
            a0 = (float)xr[j0];
            a1 = (float)xr[j1];
        }

        const f4* hv4 = (const f4*)hsh;

        // LDS region: groups 0..2
        #pragma unroll
        for (int i = 0; i < 3; ++i) {
            F4H hh; hh.v = hv4[i];
            F4H wa; wa.v = wlds[i * 1024 + j0];
            F4H wb; wb.v = wlds[i * 1024 + j1];
            #pragma unroll
            for (int q = 0; q < 4; ++q) {
                if (q & 1) { a0b = fdot2(wa.h[q], hh.h[q], a0b); a1b = fdot2(wb.h[q], hh.h[q], a1b); }
                else       { a0  = fdot2(wa.h[q], hh.h[q], a0 ); a1  = fdot2(wb.h[q], hh.h[q], a1 ); }
            }
        }
        // register region part 1: groups 3..11
        #pragma unroll
        for (int g = 0; g < 9; ++g) {
            F4H hh; hh.v = hv4[3 + g];
            F4H wa; wa.v = wrA[g];
            F4H wb; wb.v = wrB[g];
            #pragma unroll
            for (int q = 0; q < 4; ++q) {
                if (q & 1) { a0b = fdot2(wa.h[q], hh.h[q], a0b); a1b = fdot2(wb.h[q], hh.h[q], a1b); }
                else       { a0  = fdot2(wa.h[q], hh.h[q], a0 ); a1  = fdot2(wb.h[q], hh.h[q], a1 ); }
            }
        }
        // consume stream batch A (groups 21..25)
        #pragma unroll
        for (int g = 0; g < 5; ++g) {
            F4H hh; hh.v = hv4[21 + g];
            F4H wa; wa.v = sA0[g];
            F4H wb; wb.v = sA1[g];
            #pragma unroll
            for (int q = 0; q < 4; ++q) {
                if (q & 1) { a0b = fdot2(wa.h[q], hh.h[q], a0b); a1b = fdot2(wb.h[q], hh.h[q], a1b); }
                else       { a0  = fdot2(wa.h[q], hh.h[q], a0 ); a1  = fdot2(wb.h[q], hh.h[q], a1 ); }
            }
        }
        // stream batch B issue (groups 26..31)
        f4 sB0[6], sB1[6];
        #pragma unroll
        for (int g = 0; g < 6; ++g) { sB0[g] = strBp[g * 1024 + j0]; sB1[g] = strBp[g * 1024 + j1]; }
        // register region part 2: groups 12..20
        #pragma unroll
        for (int g = 9; g < 18; ++g) {
            F4H hh; hh.v = hv4[3 + g];
            F4H wa; wa.v = wrA[g];
            F4H wb; wb.v = wrB[g];
            #pragma unroll
            for (int q = 0; q < 4; ++q) {
                if (q & 1) { a0b = fdot2(wa.h[q], hh.h[q], a0b); a1b = fdot2(wb.h[q], hh.h[q], a1b); }
                else       { a0  = fdot2(wa.h[q], hh.h[q], a0 ); a1  = fdot2(wb.h[q], hh.h[q], a1 ); }
            }
        }
        // consume stream batch B (groups 26..31)
        #pragma unroll
        for (int g = 0; g < 6; ++g) {
            F4H hh; hh.v = hv4[26 + g];
            F4H wa; wa.v = sB0[g];
            F4H wb; wb.v = sB1[g];
            #pragma unroll
            for (int q = 0; q < 4; ++q) {
                if (q & 1) { a0b = fdot2(wa.h[q], hh.h[q], a0b); a1b = fdot2(wb.h[q], hh.h[q], a1b); }
                else       { a0  = fdot2(wa.h[q], hh.h[q], a0 ); a1  = fdot2(wb.h[q], hh.h[q], a1 ); }
            }
        }

        gates[j0] = a0 + a0b;
        gates[j1] = a1 + a1b;
        __syncthreads();

        if (t < 256) {
            float gi = gates[t];
            float gf = gates[t + 256];
            float gg = gates[t + 512];
            float go = gates[t + 768];
            float si = 1.f / (1.f + __expf(-gi));
            float sf = 1.f / (1.f + __expf(-gf));
            float so = 1.f / (1.f + __expf(-go));
            float tg = 1.f - 2.f / (__expf(2.f * gg) + 1.f);   // tanh, NaN-safe
            cst = sf * cst + si * tg;
            float th = 1.f - 2.f / (__expf(2.f * cst) + 1.f);
            float hvl = so * th;
            hsh[t] = (f16)hvl;
            if (LAYER == 1) hsum += hvl;
        }
        __syncthreads();

        if (t < 32) ((f4*)(houtb + (size_t)tt * NH))[t] = ((const f4*)hsh)[t];
    }
    if (LAYER == 1 && t < 256) mmean[b * NH + t] = hsum * (1.f / 512.f);
}

// ---------------- K2: x1 = h0 @ Wih1^T + bias1 (round-1 verbatim) ----------------
__global__ __launch_bounds__(256)
void k2_gemm(const f16* __restrict__ h0, const f4* __restrict__ wih1p,
             const float* __restrict__ b1c, f16* __restrict__ x1)
{
    __shared__ __align__(16) f16 ash[64 * 256];   // 32 KB A-tile (64 rows x 256 k)
    const int l = threadIdx.x;
    const size_t m0 = (size_t)blockIdx.x * 64;
    const f4* src = (const f4*)(h0 + m0 * 256);
    f4* dst = (f4*)ash;
    #pragma unroll
    for (int i = 0; i < 8; ++i) dst[l + 256 * i] = src[l + 256 * i];
    __syncthreads();

    const int lane = l & 63;
    const int rg4 = l >> 6;
    #pragma unroll 1
    for (int pass = 0; pass < 16; ++pass) {
        const int rgrp = pass >> 2;
        const int nc = pass & 3;
        const int row0 = rgrp * 16 + rg4 * 4;
        const int col0 = nc * 256 + lane;
        float acc[4][4];
        float bq[4];
        #pragma unroll
        for (int q = 0; q < 4; ++q) bq[q] = b1c[col0 + 64 * q];
        #pragma unroll
        for (int r = 0; r < 4; ++r)
            #pragma unroll
            for (int q = 0; q < 4; ++q) acc[r][q] = bq[q];

        for (int u = 0; u < 32; ++u) {
            f4 wv[4];
            #pragma unroll
            for (int q = 0; q < 4; ++q) wv[q] = wih1p[u * 1024 + col0 + 64 * q];
            #pragma unroll
            for (int r = 0; r < 4; ++r) {
                F4H av; av.v = ((const f4*)ash)[(row0 + r) * 32 + u];
                #pragma unroll
                for (int q = 0; q < 4; ++q) {
                    F4H wq; wq.v = wv[q];
                    #pragma unroll
                    for (int p = 0; p < 4; ++p) acc[r][q] = fdot2(av.h[p], wq.h[p], acc[r][q]);
                }
            }
        }
        #pragma unroll
        for (int r = 0; r < 4; ++r)
            #pragma unroll
            for (int q = 0; q < 4; ++q)
                x1[(m0 + row0 + r) * 1024 + col0 + 64 * q] = (f16)acc[r][q];
    }
}

// ---------------- K4a (round-1 verbatim) ----------------
__global__ __launch_bounds__(256)
void k4a(const f16* __restrict__ h1, const float* __restrict__ mmean,
         const float* __restrict__ Wl1, const float* __restrict__ b1,
         const f4* __restrict__ wr1p, float* __restrict__ m1sum,
         float* __restrict__ hh1last)
{
    __shared__ __align__(16) f16 ash[64 * 256];   // 32 KB h1 chunk
    __shared__ float msh[256];
    __shared__ float mbase[128];
    __shared__ float red[256];
    const int l = threadIdx.x;
    const int b = blockIdx.x >> 3;
    const int ch = blockIdx.x & 7;

    const f4* src = (const f4*)(h1 + ((size_t)b * 512 + ch * 64) * 256);
    f4* dst = (f4*)ash;
    #pragma unroll
    for (int i = 0; i < 8; ++i) dst[l + 256 * i] = src[l + 256 * i];
    msh[l] = mmean[b * 256 + l];
    __syncthreads();

    if (l < 128) {
        float acc = 0.f;
        if (l < 100) {
            acc = b1[l];
            const float* wrow = Wl1 + l * 256;
            for (int j = 0; j < 256; ++j) acc += msh[j] * wrow[j];
        }
        mbase[l] = acc;
    }
    __syncthreads();

    const int o = l & 127;
    const int th = l >> 7;
    float sumloc = 0.f;
    float last = 0.f;
    #pragma unroll 1
    for (int it = 0; it < 32; ++it) {
        const int tloc = it * 2 + th;
        float acc = mbase[o];
        const f4* arow = (const f4*)(ash + tloc * 256);
        #pragma unroll
        for (int u = 0; u < 32; ++u) {
            F4H av; av.v = arow[u];
            F4H wv; wv.v = wr1p[u * 128 + o];
            #pragma unroll
            for (int p = 0; p < 4; ++p) acc = fdot2(av.h[p], wv.h[p], acc);
        }
        float e = acc > 0.f ? acc : (__expf(acc) - 1.f);
        sumloc += e;
        if (tloc == 63) last = e;
    }
    red[l] = sumloc;
    __syncthreads();
    if (l < 128) {
        float s = red[l] + red[l + 128];
        if (l < 100) atomicAdd(m1sum + b * 128 + l, s);
    }
    if (ch == 7 && th == 1) hh1last[b * 128 + o] = last;
}

// ---------------- K4b: final head (round-1 verbatim) ----------------
__global__ __launch_bounds__(128)
void k4b(const float* __restrict__ m1sum, const float* __restrict__ hh1last,
         const float* __restrict__ Wl2, const float* __restrict__ Wr2,
         const float* __restrict__ b2,
         const float* __restrict__ Wfc1, const float* __restrict__ bfc1,
         const float* __restrict__ Wfc2, const float* __restrict__ bfc2,
         float* __restrict__ out)
{
    __shared__ float m1s[128];
    __shared__ float hl[128];
    __shared__ float s[128];
    __shared__ float zsh[512];
    const int b = blockIdx.x;
    const int l = threadIdx.x;

    m1s[l] = m1sum[b * 128 + l] * (1.f / 512.f);
    hl[l] = hh1last[b * 128 + l];
    __syncthreads();

    {
        float acc = b2[l];
        const float* wl2r = Wl2 + l * 100;
        const float* wr2r = Wr2 + l * 100;
        for (int j = 0; j < 100; ++j) acc += m1s[j] * wl2r[j] + hl[j] * wr2r[j];
        s[l] = acc;
    }
    __syncthreads();

    #pragma unroll 1
    for (int i = 0; i < 4; ++i) {
        const int idx = l + 128 * i;
        const int k = idx >> 6, o = idx & 63;
        const float* w = Wfc1 + (size_t)(k * 64 + o) * 128;
        float a = bfc1[k * 64 + o];
        for (int d = 0; d < 128; ++d) a += s[d] * w[d];
        zsh[idx] = a > 0.f ? a : 0.f;
    }
    __syncthreads();

    #pragma unroll 1
    for (int i = 0; i < 2; ++i) {
        const int idx = l + 128 * i;
        if (idx < 192) {
            const int k = idx / 24, p = idx % 24;
            const float* w = Wfc2 + (size_t)(k * 24 + p) * 64;
            float a = bfc2[k * 24 + p];
            const float* z = zsh + k * 64;
            for (int d = 0; d < 64; ++d) a += z[d] * w[d];
            out[(size_t)(k * 64 + b) * 24 + p] = a;
        }
    }
}

// ---------------- launch ----------------
extern "C" void kernel_launch(void* const* d_in, const int* in_sizes, int n_in,
                              void* d_out, int out_size, void* d_ws, size_t ws_size,
                              hipStream_t stream)
{
    const float* x    = (const float*)d_in[0];
    const float* Wih0 = (const float*)d_in[1];
    const float* Whh0 = (const float*)d_in[2];
    const float* bih0 = (const float*)d_in[3];
    const float* bhh0 = (const float*)d_in[4];
    const float* Wih1 = (const float*)d_in[5];
    const float* Whh1 = (const float*)d_in[6];
    const float* bih1 = (const float*)d_in[7];
    const float* bhh1 = (const float*)d_in[8];
    const float* Wl1  = (const float*)d_in[9];
    const float* Wr1  = (const float*)d_in[10];
    const float* b1   = (const float*)d_in[11];
    const float* Wl2  = (const float*)d_in[12];
    const float* Wr2  = (const float*)d_in[13];
    const float* b2   = (const float*)d_in[14];
    const float* Wfc1 = (const float*)d_in[15];
    const float* bfc1 = (const float*)d_in[16];
    const float* Wfc2 = (const float*)d_in[17];
    const float* bfc2 = (const float*)d_in[18];

    char* ws = (char*)d_ws;
    f16*   h0f   = (f16*)(ws + OFF_H0);
    f16*   x1f   = (f16*)(ws + OFF_X1);
    f16*   h1f   = (f16*)(ws + OFF_H1);
    f4*    pl0   = (f4*)(ws + OFF_PL0);
    f4*    pl1   = (f4*)(ws + OFF_PL1);
    f4*    wih1p = (f4*)(ws + OFF_WIH1);
    h2*    wx0p  = (h2*)(ws + OFF_WX0);
    float* b0c   = (float*)(ws + OFF_B0C);
    float* b1c   = (float*)(ws + OFF_B1C);
    f4*    wr1p  = (f4*)(ws + OFF_WR1);
    float* mm    = (float*)(ws + OFF_MM);
    float* m1s   = (float*)(ws + OFF_M1S);
    float* hhl   = (float*)(ws + OFF_HL);

    pack_w256<<<128, 256, 0, stream>>>(Whh0, pl0);
    pack_w256<<<128, 256, 0, stream>>>(Whh1, pl1);
    pack_w256<<<128, 256, 0, stream>>>(Wih1, wih1p);
    pack_misc<<<40, 256, 0, stream>>>(bih0, bhh0, bih1, bhh1, Wih0, Wr1,
                                      b0c, b1c, wx0p, wr1p);
    hipMemsetAsync(m1s, 0, 64 * 128 * sizeof(float), stream);

    lstm_chain<0><<<64, 512, 0, stream>>>(x, (const f16*)nullptr, pl0, b0c, wx0p, h0f, (float*)nullptr);
    k2_gemm<<<512, 256, 0, stream>>>(h0f, wih1p, b1c, x1f);
    lstm_chain<1><<<64, 512, 0, stream>>>((const float*)nullptr, x1f, pl1, (const float*)nullptr,
                                          (const h2*)nullptr, h1f, mm);
    k4a<<<512, 256, 0, stream>>>(h1f, mm, Wl1, b1, wr1p, m1s, hhl);
    k4b<<<64, 128, 0, stream>>>(m1s, hhl, Wl2, Wr2, b2, Wfc1, bfc1, Wfc2, bfc2, (float*)d_out);
}